// Round 1
// baseline (38.483 us; speedup 1.0000x reference)
//
#include <hip/hip_runtime.h>
#include <math.h>

// Problem shape (fixed by reference setup_inputs): x (8, 12, 4096, 64) f32.
// Group = (b, t): 768 elements x[b, h, t, c], h=0..11, c=0..63.
// out[b,h,t,c] = delta * 2^-clip(rint(-log2(max(x/delta,1e-8))),0,255), delta = group max.

#define BB 8
#define HH 12
#define TT 4096
#define CC 64

__global__ __launch_bounds__(192) void log2q_kernel(const float* __restrict__ x,
                                                    float* __restrict__ out) {
    // one block per (b,t) group; 192 threads * float4 = 768 elements
    const int g   = blockIdx.x;        // 0 .. BB*TT-1
    const int b   = g >> 12;           // / 4096
    const int t   = g & 4095;
    const int tid = threadIdx.x;       // 0..191
    const int h   = tid >> 4;          // 0..11
    const int c4  = (tid & 15) << 2;   // 0,4,...,60

    const size_t idx = (((size_t)b * HH + h) * TT + t) * CC + c4;
    const float4 xv = *reinterpret_cast<const float4*>(x + idx);

    // ---- exact max reduction over the 768-element group ----
    float m = fmaxf(fmaxf(xv.x, xv.y), fmaxf(xv.z, xv.w));
#pragma unroll
    for (int off = 32; off > 0; off >>= 1)
        m = fmaxf(m, __shfl_xor(m, off));
    __shared__ float smax[3];
    const int wave = tid >> 6;
    if ((tid & 63) == 0) smax[wave] = m;
    __syncthreads();
    const float delta = fmaxf(fmaxf(smax[0], smax[1]), smax[2]);

    const float r[4] = {xv.x, xv.y, xv.z, xv.w};
    float o[4];
#pragma unroll
    for (int j = 0; j < 4; ++j) {
        // IEEE f32 division to match jnp's lax.div bit-exactly
        const float ratio = fmaxf(r[j] / delta, 1e-8f);

        // fast path: hardware v_log_f32
        const float nv = -__log2f(ratio);
        float xi = rintf(nv);
        const float d = fabsf(nv - xi);
        if (0.5f - d < 1e-4f) {
            // near a half-integer cliff: replicate jnp.log2 = log(x)/log(2)
            // with a correctly-rounded f32 log, then IEEE f32 divide, then
            // round-half-even (matches jnp.round).
            const float tt = (float)log((double)ratio);
            const float v2 = tt / 0x1.62e43p-1f;  // fl32(ln 2)
            xi = rintf(-v2);
        }
        // x_quant = clip(x_int/255, 0, 1) * 255  (replicated with IEEE ops)
        const float q = fminf(fmaxf(xi / 255.0f, 0.0f), 1.0f) * 255.0f;
        // 2^-q : exact for integer q (matches ref's pow(2,-q)); faithful else
        const float p = exp2f(-q);
        o[j] = (xi >= 256.0f) ? 0.0f : delta * p;
    }

    const float4 ov = {o[0], o[1], o[2], o[3]};
    *reinterpret_cast<float4*>(out + idx) = ov;
}

extern "C" void kernel_launch(void* const* d_in, const int* in_sizes, int n_in,
                              void* d_out, int out_size, void* d_ws, size_t ws_size,
                              hipStream_t stream) {
    const float* x = (const float*)d_in[0];
    float* out = (float*)d_out;
    dim3 grid(BB * TT);   // 32768 blocks, one per (b,t)
    dim3 block(192);
    log2q_kernel<<<grid, block, 0, stream>>>(x, out);
}